// Round 4
// baseline (233.237 us; speedup 1.0000x reference)
//
#include <hip/hip_runtime.h>
#include <hip/hip_bf16.h>

// Problem constants (fixed by the reference file)
#define LEAFN 1024
#define NN    2048            // nodes per batch incl. global node 0
#define BATCH 8
#define DD    128
#define ROWS  (BATCH*NN)      // 16384
#define AHS   256             // ah row stride: [agg(128) | h(128)] bf16

// ln(10000)/32
#define LOG1E4_OVER_32 0.28782313662425575f

typedef __bf16 bf16x8 __attribute__((ext_vector_type(8)));
typedef float  floatx4 __attribute__((ext_vector_type(4)));

__device__ __forceinline__ float bf2f(unsigned short u) {
  return __uint_as_float(((unsigned)u) << 16);
}
__device__ __forceinline__ unsigned short f2bf(float f) {
  unsigned u = __float_as_uint(f);
  u += 0x7FFFu + ((u >> 16) & 1u);          // round-to-nearest-even
  return (unsigned short)(u >> 16);
}
__device__ __forceinline__ float gelu(float v) {
  return 0.5f * v * (1.0f + erff(v * 0.70710678118f));
}
// uint = two packed bf16 (little-endian: elem0 = low half)
__device__ __forceinline__ void cvt8(uint4 u, float* f) {
  f[0] = __uint_as_float(u.x << 16); f[1] = __uint_as_float(u.x & 0xffff0000u);
  f[2] = __uint_as_float(u.y << 16); f[3] = __uint_as_float(u.y & 0xffff0000u);
  f[4] = __uint_as_float(u.z << 16); f[5] = __uint_as_float(u.z & 0xffff0000u);
  f[6] = __uint_as_float(u.w << 16); f[7] = __uint_as_float(u.w & 0xffff0000u);
}

__device__ __forceinline__ float enc_val(int node, int d) {
  float hp, vp;
  if (node == 0) { hp = -0.5f; vp = -1.0f; }
  else {
    int v = 31 - __clz(node);
    hp = (float)(node - (1 << v));
    vp = (float)v;
  }
  float pos = (d < 64) ? hp : vp;
  int i = ((d < 64) ? d : (d - 64)) >> 1;
  float inv = expf(-(float)i * LOG1E4_OVER_32);
  float ang = pos * inv;
  return (d & 1) ? cosf(ang) : sinf(ang);
}

// ---------------------------------------------------------------------------
// CSR segment bounds from globally-sorted dst (node 0 per batch: empty).
__global__ void k_csr(const int* __restrict__ dst, int E,
                      int* __restrict__ s0, int* __restrict__ s1) {
  int i = blockIdx.x * blockDim.x + threadIdx.x;
  if (i < BATCH) { s0[i * NN] = 0; s1[i * NN] = 0; }
  if (i >= E) return;
  int dv = dst[i];
  if (i == 0 || dst[i - 1] != dv) s0[dv] = i;
  if (i == E - 1 || dst[i + 1] != dv) s1[dv] = i + 1;
}

// ---------------------------------------------------------------------------
// Weight repack into B-fragment order for mfma_f32_16x16x32_bf16.
__global__ __launch_bounds__(256) void k_repack(const float* __restrict__ wn,
                                                const float* __restrict__ wr,
                                                unsigned short* __restrict__ wf) {
  int l = blockIdx.y;
  int idx = blockIdx.x * 256 + threadIdx.x;   // 0..4095
  int lane = idx & 63, ct = (idx >> 6) & 7, kc = idx >> 9;
  int n = ct * 16 + (lane & 15);
  int k = kc * 32 + (lane >> 4) * 8;
  const float* w = (k < 128) ? (wn + (size_t)l * DD * DD) : (wr + (size_t)l * DD * DD);
  int kk = k & 127;
  unsigned short* o = wf + (size_t)l * 32768 + (size_t)idx * 8;
#pragma unroll
  for (int j = 0; j < 8; ++j) o[j] = f2bf(w[(size_t)(kk + j) * DD + n]);
}

// ---------------------------------------------------------------------------
// Tree build + layer-0 LN/GELU for depth>=4 nodes.
__global__ __launch_bounds__(256) void k_tree(const float* __restrict__ elements,
                                              float* __restrict__ x,
                                              float* __restrict__ lvl4,
                                              unsigned short* __restrict__ ah,
                                              const float* __restrict__ gamma,
                                              const float* __restrict__ beta) {
  __shared__ float sm[127 * DD];
  int b = blockIdx.x >> 4, s = blockIdx.x & 15;
  const float4* src = (const float4*)(elements + (size_t)(b * LEAFN + s * 64) * DD);
  for (int i = threadIdx.x; i < 2048; i += 256) {
    int f = i * 4;
    int j = f >> 7, d = f & 127;
    *(float4*)&sm[(63 + j) * DD + d] = src[i];
  }
  __syncthreads();
  for (int lv = 5; lv >= 0; --lv) {
    int nodes = 1 << lv;
    for (int idx = threadIdx.x; idx < nodes * DD; idx += 256) {
      int k = nodes + (idx >> 7);
      int d = idx & 127;
      sm[(k - 1) * DD + d] = 0.5f * (sm[(2 * k - 1) * DD + d] + sm[(2 * k) * DD + d]);
    }
    __syncthreads();
  }
  // stash raw level-4 feature before overwrite
  if (threadIdx.x < DD) lvl4[(b * 16 + s) * DD + threadIdx.x] = sm[threadIdx.x];
  __syncthreads();
  // x = feat + enc; keep in sm
  for (int idx = threadIdx.x; idx < 127 * DD; idx += 256) {
    int k = (idx >> 7) + 1;
    int d = idx & 127;
    int lv = 31 - __clz(k);
    int g = ((16 + s) << lv) | (k - (1 << lv));
    float xv = sm[idx] + enc_val(g, d);
    x[((size_t)(b * NN + g)) * DD + d] = xv;
    sm[idx] = xv;
  }
  __syncthreads();
  // LN + GELU -> bf16 h. 8 threads/row, 16 dims each.
  int sub = threadIdx.x & 7, dp = sub * 16;
  float gm[16], bt[16];
#pragma unroll
  for (int j = 0; j < 16; ++j) { gm[j] = gamma[dp + j]; bt[j] = beta[dp + j]; }
  for (int rr = threadIdx.x >> 3; rr < 127; rr += 32) {
    float v[16], s1 = 0.f, s2 = 0.f;
#pragma unroll
    for (int j = 0; j < 16; ++j) { v[j] = sm[rr * DD + dp + j]; s1 += v[j]; s2 += v[j] * v[j]; }
    s1 += __shfl_xor(s1, 1); s2 += __shfl_xor(s2, 1);
    s1 += __shfl_xor(s1, 2); s2 += __shfl_xor(s2, 2);
    s1 += __shfl_xor(s1, 4); s2 += __shfl_xor(s2, 4);
    float mu = s1 * (1.0f / 128.0f);
    float var = s2 * (1.0f / 128.0f) - mu * mu;
    float rinv = rsqrtf(var + 1e-5f);
    int k = rr + 1, lv = 31 - __clz(k);
    int g = ((16 + s) << lv) | (k - (1 << lv));
    unsigned short o[16];
#pragma unroll
    for (int j = 0; j < 16; ++j)
      o[j] = f2bf(gelu((v[j] - mu) * rinv * gm[j] + bt[j]));
    unsigned short* dst = &ah[(size_t)(b * NN + g) * AHS + 128 + dp];
#pragma unroll
    for (int j = 0; j < 4; ++j) *(ushort4*)&dst[j * 4] = *(ushort4*)&o[j * 4];
  }
}

// ---------------------------------------------------------------------------
// Top nodes 0..15 per batch: finish tree, write x and layer-0 h.
__global__ __launch_bounds__(128) void k_top(const float* __restrict__ lvl4,
                                             float* __restrict__ x,
                                             unsigned short* __restrict__ ah,
                                             const float* __restrict__ gamma,
                                             const float* __restrict__ beta) {
  __shared__ float xs[16][DD];
  int b = blockIdx.x, d = threadIdx.x;   // 128 threads
  float v[16];
  for (int j = 0; j < 16; ++j) v[j] = lvl4[(b * 16 + j) * DD + d];
  for (int j = 0; j < 8; ++j) v[j] = 0.5f * (v[2 * j] + v[2 * j + 1]);
  for (int j = 0; j < 8; ++j) xs[8 + j][d] = v[j] + enc_val(8 + j, d);
  for (int j = 0; j < 4; ++j) v[j] = 0.5f * (v[2 * j] + v[2 * j + 1]);
  for (int j = 0; j < 4; ++j) xs[4 + j][d] = v[j] + enc_val(4 + j, d);
  for (int j = 0; j < 2; ++j) v[j] = 0.5f * (v[2 * j] + v[2 * j + 1]);
  for (int j = 0; j < 2; ++j) xs[2 + j][d] = v[j] + enc_val(2 + j, d);
  v[0] = 0.5f * (v[0] + v[1]);
  xs[1][d] = v[0] + enc_val(1, d);
  xs[0][d] = -1.0f + enc_val(0, d);
  for (int j = 0; j < 16; ++j) x[((size_t)(b * NN + j)) * DD + d] = xs[j][d];
  __syncthreads();
  // LN + GELU: 8 threads/row x 16 rows
  int rr = threadIdx.x >> 3, sub = threadIdx.x & 7, dp = sub * 16;
  float w[16], s1 = 0.f, s2 = 0.f;
#pragma unroll
  for (int j = 0; j < 16; ++j) { w[j] = xs[rr][dp + j]; s1 += w[j]; s2 += w[j] * w[j]; }
  s1 += __shfl_xor(s1, 1); s2 += __shfl_xor(s2, 1);
  s1 += __shfl_xor(s1, 2); s2 += __shfl_xor(s2, 2);
  s1 += __shfl_xor(s1, 4); s2 += __shfl_xor(s2, 4);
  float mu = s1 * (1.0f / 128.0f);
  float var = s2 * (1.0f / 128.0f) - mu * mu;
  float rinv = rsqrtf(var + 1e-5f);
  unsigned short o[16];
#pragma unroll
  for (int j = 0; j < 16; ++j)
    o[j] = f2bf(gelu((w[j] - mu) * rinv * gamma[dp + j] + beta[dp + j]));
  unsigned short* dst = &ah[(size_t)(b * NN + rr) * AHS + 128 + dp];
#pragma unroll
  for (int j = 0; j < 4; ++j) *(ushort4*)&dst[j * 4] = *(ushort4*)&o[j * 4];
}

// ---------------------------------------------------------------------------
// Internal-node aggregation part 1: subtree sums per 64-leaf subtree.
__global__ __launch_bounds__(256) void k_aggsub(unsigned short* ah,
                                                const int* __restrict__ s0a,
                                                const int* __restrict__ s1a,
                                                float* __restrict__ sroot) {
  __shared__ floatx4 S[64][32];
  int b = blockIdx.x >> 4, s = blockIdx.x & 15;

  for (int idx = threadIdx.x; idx < 32 * 32; idx += 256) {
    int k = 32 + (idx >> 5), q = idx & 31;
    int c = (16 + s) * 64 + (2 * k - 64);
    size_t a0 = (size_t)(b * NN + c) * AHS + 128 + q * 4;
    ushort4 u0 = *(const ushort4*)&ah[a0];
    ushort4 u1 = *(const ushort4*)&ah[a0 + AHS];
    floatx4 v;
    v[0] = bf2f(u0.x) + bf2f(u1.x);
    v[1] = bf2f(u0.y) + bf2f(u1.y);
    v[2] = bf2f(u0.z) + bf2f(u1.z);
    v[3] = bf2f(u0.w) + bf2f(u1.w);
    S[k][q] = v;
    int g = (16 + s) * 32 + (k - 32);
    int r = b * NN + g;
    float inv = 1.0f / (float)max(s1a[r] - s0a[r], 1);
    ushort4 o;
    o.x = f2bf(v[0] * inv); o.y = f2bf(v[1] * inv);
    o.z = f2bf(v[2] * inv); o.w = f2bf(v[3] * inv);
    *(ushort4*)&ah[(size_t)r * AHS + q * 4] = o;
  }
  __syncthreads();
  for (int lv = 4; lv >= 0; --lv) {
    int nk = 1 << lv;
    for (int idx = threadIdx.x; idx < nk * 32; idx += 256) {
      int k = nk + (idx >> 5), q = idx & 31;
      int c = ((16 + s) << (lv + 1)) | (2 * k - 2 * nk);
      size_t a0 = (size_t)(b * NN + c) * AHS + 128 + q * 4;
      ushort4 u0 = *(const ushort4*)&ah[a0];
      ushort4 u1 = *(const ushort4*)&ah[a0 + AHS];
      floatx4 sc0 = S[2 * k][q], sc1 = S[2 * k + 1][q];
      floatx4 v;
      v[0] = bf2f(u0.x) + bf2f(u1.x) + sc0[0] + sc1[0];
      v[1] = bf2f(u0.y) + bf2f(u1.y) + sc0[1] + sc1[1];
      v[2] = bf2f(u0.z) + bf2f(u1.z) + sc0[2] + sc1[2];
      v[3] = bf2f(u0.w) + bf2f(u1.w) + sc0[3] + sc1[3];
      S[k][q] = v;
      int g = ((16 + s) << lv) | (k - nk);
      int r = b * NN + g;
      float inv = 1.0f / (float)max(s1a[r] - s0a[r], 1);
      ushort4 o;
      o.x = f2bf(v[0] * inv); o.y = f2bf(v[1] * inv);
      o.z = f2bf(v[2] * inv); o.w = f2bf(v[3] * inv);
      *(ushort4*)&ah[(size_t)r * AHS + q * 4] = o;
    }
    __syncthreads();
  }
  for (int q = threadIdx.x; q < 32; q += 256)
    ((floatx4*)sroot)[(size_t)(b * 16 + s) * 32 + q] = S[1][q];
}

// ---------------------------------------------------------------------------
// Leaf-row aggregation with per-level LDS window cache + top-16 finish.
// Blocks 0..255: 32 leaves each. Blocks 256..263: top nodes per batch.
#define SLACK 10
#define CACHE_ROWS 220
#define CSTRIDE 136
__global__ __launch_bounds__(256) void k_leafagg(const int* __restrict__ src,
                                                 const int* __restrict__ s0a,
                                                 const int* __restrict__ s1a,
                                                 const float* __restrict__ sroot,
                                                 unsigned short* ah) {
  if (blockIdx.x >= 256) {
    int b = blockIdx.x - 256, d = threadIdx.x;
    if (d >= 128) return;
    float S16[16], h16[16], Sv[16];
#pragma unroll
    for (int j = 0; j < 16; ++j) S16[j] = sroot[(size_t)(b * 16 + j) * DD + d];
#pragma unroll
    for (int j = 0; j < 16; ++j)
      h16[j] = bf2f(ah[(size_t)(b * NN + 16 + j) * AHS + 128 + d]);
#pragma unroll
    for (int k = 8; k < 16; ++k)
      Sv[k] = h16[2 * k - 16] + h16[2 * k - 15] + S16[2 * k - 16] + S16[2 * k - 15];
#pragma unroll
    for (int k = 7; k >= 1; --k)
      Sv[k] = bf2f(ah[(size_t)(b * NN + 2 * k) * AHS + 128 + d]) +
              bf2f(ah[(size_t)(b * NN + 2 * k + 1) * AHS + 128 + d]) +
              Sv[2 * k] + Sv[2 * k + 1];
#pragma unroll
    for (int k = 1; k < 16; ++k) {
      int r = b * NN + k;
      float inv = 1.0f / (float)max(s1a[r] - s0a[r], 1);
      ah[(size_t)r * AHS + d] = f2bf(Sv[k] * inv);
    }
    ah[(size_t)(b * NN) * AHS + d] = f2bf(0.0f);
    return;
  }

  __shared__ unsigned short cache[CACHE_ROWS * CSTRIDE];
  int b = blockIdx.x >> 5, jb = blockIdx.x & 31;
  int li0 = jb * 32;
  int g0 = 1024 + li0, g1 = g0 + 31;

  // per-level cache bounds (same scalar computation in every thread)
  int lo[11], wd[11], off[11];
  int acc_off = 0;
  for (int cd = 10; cd >= 1; --cd) {
    int a0 = g0 >> (10 - cd), a1 = g1 >> (10 - cd);
    int l = a0 - SLACK, hgh = a1 + SLACK;
    int lvlo = 1 << cd, lvhi = (2 << cd) - 1;
    l = l < lvlo ? lvlo : l;
    hgh = hgh > lvhi ? lvhi : hgh;
    int w = hgh - l + 1;
    if (acc_off + w > CACHE_ROWS) w = CACHE_ROWS - acc_off;   // defensive
    if (w < 0) w = 0;
    lo[cd] = l; wd[cd] = w; off[cd] = acc_off; acc_off += w;
  }
  // load cache rows (h halves, bf16), coalesced uint4
  for (int cd = 10; cd >= 1; --cd) {
    int w = wd[cd];
    for (int t = threadIdx.x; t < w * 16; t += 256) {
      int row = t >> 4, seg = t & 15;
      *(uint4*)&cache[(off[cd] + row) * CSTRIDE + seg * 8] =
          *(const uint4*)&ah[(size_t)(b * NN + lo[cd] + row) * AHS + 128 + seg * 8];
    }
  }
  __syncthreads();

  int leaf = li0 + (threadIdx.x >> 3);
  int dp = (threadIdx.x & 7) * 16;
  int r = b * NN + 1024 + leaf;
  int e0 = s0a[r], e1 = s1a[r];
  float acc[16];
#pragma unroll
  for (int j = 0; j < 16; ++j) acc[j] = 0.f;
  for (int e = e0; e < e1; ++e) {
    int g = src[e] - b * NN;
    int lv = 31 - __clz(g);
    int idx = g - lo[lv];
    float f[16];
    if ((unsigned)idx < (unsigned)wd[lv]) {
      const unsigned short* p = &cache[(off[lv] + idx) * CSTRIDE + dp];
      cvt8(*(const uint4*)p, f);
      cvt8(*(const uint4*)(p + 8), f + 8);
    } else {
      const unsigned short* p = &ah[(size_t)(b * NN + g) * AHS + 128 + dp];
      cvt8(*(const uint4*)p, f);
      cvt8(*(const uint4*)(p + 8), f + 8);
    }
#pragma unroll
    for (int j = 0; j < 16; ++j) acc[j] += f[j];
  }
  float inv = 1.0f / (float)max(e1 - e0, 1);
  unsigned short o[16];
#pragma unroll
  for (int j = 0; j < 16; ++j) o[j] = f2bf(acc[j] * inv);
  unsigned short* dst = &ah[(size_t)r * AHS + dp];
#pragma unroll
  for (int j = 0; j < 4; ++j) *(ushort4*)&dst[j * 4] = *(ushort4*)&o[j * 4];
}

// ---------------------------------------------------------------------------
// x += [agg|h] @ [Wn;Wr] + bias (bf16 MFMA). If write_h: fuse next layer's
// LayerNorm+GELU and write h' to ah.
__global__ __launch_bounds__(256) void k_gemm(const unsigned short* __restrict__ ah_c,
                                              const unsigned short* __restrict__ wfl,
                                              const float* __restrict__ bn,
                                              float* __restrict__ x,
                                              const float* __restrict__ gamma,
                                              const float* __restrict__ beta,
                                              unsigned short* ah_w, int write_h) {
  int wave = threadIdx.x >> 6, lane = threadIdx.x & 63;
  int r0 = blockIdx.x * 128 + wave * 32;
  int m = lane & 15, q = lane >> 4;
  const bf16x8* A0 = (const bf16x8*)(ah_c + (size_t)(r0 + m) * AHS + q * 8);
  const bf16x8* A1 = (const bf16x8*)(ah_c + (size_t)(r0 + 16 + m) * AHS + q * 8);
  const bf16x8* B  = (const bf16x8*)wfl + lane;
  floatx4 acc[2][8];
#pragma unroll
  for (int i = 0; i < 2; ++i)
#pragma unroll
    for (int ct = 0; ct < 8; ++ct) acc[i][ct] = (floatx4){0.f, 0.f, 0.f, 0.f};

#pragma unroll
  for (int kc = 0; kc < 8; ++kc) {
    bf16x8 a0 = A0[kc * 4];
    bf16x8 a1 = A1[kc * 4];
#pragma unroll
    for (int ct = 0; ct < 8; ++ct) {
      bf16x8 bb = B[(kc * 8 + ct) * 64];
      acc[0][ct] = __builtin_amdgcn_mfma_f32_16x16x32_bf16(a0, bb, acc[0][ct], 0, 0, 0);
      acc[1][ct] = __builtin_amdgcn_mfma_f32_16x16x32_bf16(a1, bb, acc[1][ct], 0, 0, 0);
    }
  }
  float s1[2][4], s2[2][4];
#pragma unroll
  for (int i = 0; i < 2; ++i)
#pragma unroll
    for (int r = 0; r < 4; ++r) { s1[i][r] = 0.f; s2[i][r] = 0.f; }
#pragma unroll
  for (int i = 0; i < 2; ++i)
#pragma unroll
    for (int ct = 0; ct < 8; ++ct) {
      int col = ct * 16 + m;
      float bias = bn[col];
#pragma unroll
      for (int r = 0; r < 4; ++r) {
        int row = r0 + i * 16 + q * 4 + r;
        float v = x[(size_t)row * DD + col] + acc[i][ct][r] + bias;
        x[(size_t)row * DD + col] = v;
        acc[i][ct][r] = v;
        s1[i][r] += v; s2[i][r] += v * v;
      }
    }
  if (write_h) {
#pragma unroll
    for (int i = 0; i < 2; ++i)
#pragma unroll
      for (int r = 0; r < 4; ++r) {
        float a = s1[i][r], bq = s2[i][r];
        a += __shfl_xor(a, 1); bq += __shfl_xor(bq, 1);
        a += __shfl_xor(a, 2); bq += __shfl_xor(bq, 2);
        a += __shfl_xor(a, 4); bq += __shfl_xor(bq, 4);
        a += __shfl_xor(a, 8); bq += __shfl_xor(bq, 8);
        float mu = a * (1.0f / 128.0f);
        float var = bq * (1.0f / 128.0f) - mu * mu;
        s1[i][r] = mu;
        s2[i][r] = rsqrtf(var + 1e-5f);
      }
#pragma unroll
    for (int i = 0; i < 2; ++i)
#pragma unroll
      for (int ct = 0; ct < 8; ++ct) {
        int col = ct * 16 + m;
        float gm = gamma[col], bt = beta[col];
#pragma unroll
        for (int r = 0; r < 4; ++r) {
          int row = r0 + i * 16 + q * 4 + r;
          float hh = gelu((acc[i][ct][r] - s1[i][r]) * s2[i][r] * gm + bt);
          ah_w[(size_t)row * AHS + 128 + col] = f2bf(hh);
        }
      }
  }
}

// ---------------------------------------------------------------------------
extern "C" void kernel_launch(void* const* d_in, const int* in_sizes, int n_in,
                              void* d_out, int out_size, void* d_ws, size_t ws_size,
                              hipStream_t stream) {
  const float* elements = (const float*)d_in[0];
  const float* ln_gamma = (const float*)d_in[1];
  const float* ln_beta  = (const float*)d_in[2];
  const float* w_nei    = (const float*)d_in[3];
  const float* b_nei    = (const float*)d_in[4];
  const float* w_root   = (const float*)d_in[5];
  const int*   edge     = (const int*)d_in[6];
  int E = in_sizes[6] / 2;
  const int* srcv = edge;
  const int* dstv = edge + E;
  float* x = (float*)d_out;

  char* ws = (char*)d_ws;
  int*            s0    = (int*)ws;                       // 64 KB
  int*            s1    = (int*)(ws + 65536);             // 64 KB
  float*          lvl4  = (float*)(ws + 131072);          // 64 KB
  float*          sroot = (float*)(ws + 196608);          // 64 KB
  unsigned short* wf    = (unsigned short*)(ws + 262144); // 128 KB
  unsigned short* ah    = (unsigned short*)(ws + 393216); // 8 MB

  k_csr<<<dim3((E + 255) / 256), dim3(256), 0, stream>>>(dstv, E, s0, s1);
  k_repack<<<dim3(16, 2), dim3(256), 0, stream>>>(w_nei, w_root, wf);
  k_tree<<<dim3(BATCH * 16), dim3(256), 0, stream>>>(elements, x, lvl4, ah, ln_gamma, ln_beta);
  k_top<<<dim3(BATCH), dim3(128), 0, stream>>>(lvl4, x, ah, ln_gamma, ln_beta);
  for (int l = 0; l < 2; ++l) {
    k_aggsub<<<dim3(BATCH * 16), dim3(256), 0, stream>>>(ah, s0, s1, sroot);
    k_leafagg<<<dim3(256 + BATCH), dim3(256), 0, stream>>>(srcv, s0, s1, sroot, ah);
    k_gemm<<<dim3(ROWS / 128), dim3(256), 0, stream>>>(
        ah, wf + (size_t)l * 32768, b_nei + l * DD, x,
        ln_gamma + DD, ln_beta + DD, ah, (l == 0) ? 1 : 0);
  }
}